// Round 1
// baseline (346.312 us; speedup 1.0000x reference)
//
#include <hip/hip_runtime.h>

// FourierFilter: per-(b,c) rfft-4096 -> top-k (80% energy) spectral mask -> irfft.
// x:[32,4096,128] f32. out = concat(x_var, x_inv), each [32,4096,128].
// Pipeline: transpose -> per-series FFT/filter/iFFT (in-place on transposed buf) -> transpose back + subtract.

#define TLEN 4096
#define N2   2048
#define CCH  128
#define BB   32
#define NSER (BB * CCH)
#define HALF 16777216  // 32*4096*128

// LDS pad swizzle: +1 float per 32 to break power-of-2 bank strides
#define LP(i) ((i) + ((i) >> 5))

__device__ __forceinline__ void dft4(float vr[4], float vi[4], float s) {
  float t0r = vr[0] + vr[2], t0i = vi[0] + vi[2];
  float t1r = vr[0] - vr[2], t1i = vi[0] - vi[2];
  float t2r = vr[1] + vr[3], t2i = vi[1] + vi[3];
  float d3r = vr[1] - vr[3], d3i = vi[1] - vi[3];
  float t3r = -s * d3i, t3i = s * d3r;      // s*i*(v1-v3)
  vr[0] = t0r + t2r; vi[0] = t0i + t2i;
  vr[1] = t1r + t3r; vi[1] = t1i + t3i;
  vr[2] = t0r - t2r; vi[2] = t0i - t2i;
  vr[3] = t1r - t3r; vi[3] = t1i - t3i;
}

__device__ __forceinline__ void dft8(float vr[8], float vi[8], float s) {
  float er[4]  = {vr[0], vr[2], vr[4], vr[6]};
  float ei[4]  = {vi[0], vi[2], vi[4], vi[6]};
  float odr[4] = {vr[1], vr[3], vr[5], vr[7]};
  float odi[4] = {vi[1], vi[3], vi[5], vi[7]};
  dft4(er, ei, s);
  dft4(odr, odi, s);
  const float c = 0.70710678118654752440f;
  float wr[4] = {1.0f, c, 0.0f, -c};
  float wi[4] = {0.0f, s * c, s, s * c};    // w^k = e^{s*i*pi*k/4}
  #pragma unroll
  for (int k = 0; k < 4; ++k) {
    float tr = wr[k] * odr[k] - wi[k] * odi[k];
    float ti = wr[k] * odi[k] + wi[k] * odr[k];
    vr[k]     = er[k] + tr; vi[k]     = ei[k] + ti;
    vr[k + 4] = er[k] - tr; vi[k + 4] = ei[k] - ti;
  }
}

// Stockham radix-8 stage, N=2048, 256 threads, j = tid. In-place (read all / barrier / write all).
__device__ __forceinline__ void stage8(float* zr, float* zi, int tid, int Ns, float s) {
  int j = tid;
  int p = j & (Ns - 1);
  float ang0 = s * 6.28318530717958647692f * (float)p / (float)(Ns * 8);
  float vr[8], vi[8];
  #pragma unroll
  for (int r = 0; r < 8; ++r) {
    int idx = LP(j + (r << 8));
    float ar = zr[idx], ai = zi[idx];
    float sn, cs;
    __sincosf(ang0 * (float)r, &sn, &cs);
    vr[r] = ar * cs - ai * sn;
    vi[r] = ar * sn + ai * cs;
  }
  dft8(vr, vi, s);
  __syncthreads();
  int idxD = ((j - p) << 3) + p;  // (j/Ns)*(Ns*8) + p
  #pragma unroll
  for (int r = 0; r < 8; ++r) {
    int idx = LP(idxD + r * Ns);
    zr[idx] = vr[r]; zi[idx] = vi[r];
  }
  __syncthreads();
}

// Final radix-4 stage, Ns=512: read/write indices coincide per j -> no intra-stage barrier needed.
__device__ __forceinline__ void stage4_last(float* zr, float* zi, int tid, float s) {
  #pragma unroll
  for (int half = 0; half < 2; ++half) {
    int j = tid + (half << 8);    // 0..511
    float ang0 = s * 6.28318530717958647692f * (float)j / 2048.0f;
    float vr[4], vi[4];
    #pragma unroll
    for (int r = 0; r < 4; ++r) {
      int idx = LP(j + (r << 9));
      float ar = zr[idx], ai = zi[idx];
      float sn, cs;
      __sincosf(ang0 * (float)r, &sn, &cs);
      vr[r] = ar * cs - ai * sn;
      vi[r] = ar * sn + ai * cs;
    }
    dft4(vr, vi, s);
    #pragma unroll
    for (int r = 0; r < 4; ++r) {
      int idx = LP(j + (r << 9));
      zr[idx] = vr[r]; zi[idx] = vi[r];
    }
  }
  __syncthreads();
}

__device__ __forceinline__ void fft2048(float* zr, float* zi, int tid, float s) {
  stage8(zr, zi, tid, 1, s);
  stage8(zr, zi, tid, 8, s);
  stage8(zr, zi, tid, 64, s);
  stage4_last(zr, zi, tid, s);
}

__device__ __forceinline__ double block_sum(double v, double* red, int tid) {
  #pragma unroll
  for (int o = 32; o > 0; o >>= 1) v += __shfl_down(v, o, 64);
  if ((tid & 63) == 0) red[tid >> 6] = v;
  __syncthreads();
  double t = red[0] + red[1] + red[2] + red[3];
  __syncthreads();
  return t;
}

// One block (256 thr) per series. buf layout: [series][4096] contiguous. In-place filter.
__global__ __launch_bounds__(256) void fourier_filter_series(float* __restrict__ buf) {
  __shared__ float zr[2112], zi[2112];     // LP(2047)=2110
  __shared__ float Xr[2113], Xi[2113];     // LP(2048)=2112
  __shared__ double red[4];
  int tid = threadIdx.x;
  float* p = buf + (size_t)blockIdx.x * TLEN;

  // Load packed: z[m] = x[2m] + i*x[2m+1]
  const float2* p2 = (const float2*)p;
  for (int k = tid; k < N2; k += 256) {
    float2 v = p2[k];
    zr[LP(k)] = v.x; zi[LP(k)] = v.y;
  }
  __syncthreads();

  fft2048(zr, zi, tid, -1.0f);   // forward

  // Unpack to rfft bins X[0..2048]:
  // E=(Z[k]+conj(Z[N-k]))/2, O=-i/2(Z[k]-conj(Z[N-k])), X[k]=E+W*O, W=e^{-i pi k/2048}
  // X[2048-k] = conj(E - W*O)
  for (int k = tid; k <= 1024; k += 256) {
    int mk = (N2 - k) & (N2 - 1);
    float akr = zr[LP(k)],  aki = zi[LP(k)];
    float bkr = zr[LP(mk)], bki = zi[LP(mk)];
    float Er  = 0.5f * (akr + bkr);
    float Ei  = 0.5f * (aki - bki);
    float Or_ = 0.5f * (aki + bki);
    float Oi  = 0.5f * (bkr - akr);
    float sn, cs;
    __sincosf(-3.14159265358979323846f * (float)k / 2048.0f, &sn, &cs);
    float tr = cs * Or_ - sn * Oi;
    float ti = cs * Oi + sn * Or_;
    Xr[LP(k)] = Er + tr;         Xi[LP(k)] = Ei + ti;
    Xr[LP(N2 - k)] = Er - tr;    Xi[LP(N2 - k)] = -(Ei - ti);
  }
  __syncthreads();

  // Energies into registers: k = tid + 256*jj  (jj=8 covers k=2048 for tid 0)
  float eb[9];
  double tloc = 0.0;
  #pragma unroll
  for (int jj = 0; jj < 9; ++jj) {
    int k = tid + (jj << 8);
    if (k <= N2) {
      float xr = Xr[LP(k)], xi = Xi[LP(k)];
      eb[jj] = xr * xr + xi * xi;
      tloc += (double)eb[jj];
    } else {
      eb[jj] = -1.0f;
    }
  }
  double total = block_sum(tloc, red, tid);
  double thresh = 0.8 * total;

  // Bitwise binary search for tau = E_k = max tau s.t. sum(e >= tau) > 0.8*total.
  unsigned lo = 0u, hi = 0x7F7FFFFFu;
  for (int it = 0; it < 31; ++it) {
    unsigned mid = (unsigned)(((unsigned long long)lo + (unsigned long long)hi + 1ull) >> 1);
    float tau = __uint_as_float(mid);
    double loc = 0.0;
    #pragma unroll
    for (int jj = 0; jj < 9; ++jj)
      if (eb[jj] >= tau) loc += (double)eb[jj];
    double ssum = block_sum(loc, red, tid);
    if (ssum > thresh) lo = mid; else hi = mid - 1;
  }
  float tau = __uint_as_float(lo);

  // Mask (zero bins with e >= tau) + hermitian repack:
  // E=(X[k]+conj(X[N-k]))/2, O=e^{+i pi k/2048}*(X[k]-conj(X[N-k]))/2, Z[k]=E+iO
  for (int k = tid; k < N2; k += 256) {
    int mk = N2 - k;
    float xkr = Xr[LP(k)],  xki = Xi[LP(k)];
    float xmr = Xr[LP(mk)], xmi = Xi[LP(mk)];
    float ek = xkr * xkr + xki * xki;
    float em = xmr * xmr + xmi * xmi;
    if (ek >= tau) { xkr = 0.0f; xki = 0.0f; }
    if (em >= tau) { xmr = 0.0f; xmi = 0.0f; }
    float Er = 0.5f * (xkr + xmr);
    float Ei = 0.5f * (xki - xmi);
    float Br = 0.5f * (xkr - xmr);
    float Bi = 0.5f * (xki + xmi);
    float sn, cs;
    __sincosf(3.14159265358979323846f * (float)k / 2048.0f, &sn, &cs);
    float Or_ = cs * Br - sn * Bi;
    float Oi  = cs * Bi + sn * Br;
    zr[LP(k)] = Er - Oi;
    zi[LP(k)] = Ei + Or_;
  }
  __syncthreads();

  fft2048(zr, zi, tid, 1.0f);    // inverse (unscaled)

  const float scale = 1.0f / 2048.0f;
  float2* po = (float2*)p;
  for (int k = tid; k < N2; k += 256) {
    float2 v;
    v.x = zr[LP(k)] * scale;
    v.y = zi[LP(k)] * scale;
    po[k] = v;
  }
}

// x[B,T,C] -> xT[B,C,T]
__global__ __launch_bounds__(256) void transpose_fwd(const float* __restrict__ x, float* __restrict__ xT) {
  __shared__ float tile[32][33];
  int t0 = blockIdx.x << 5, c0 = blockIdx.y << 5, b = blockIdx.z;
  int col = threadIdx.x & 31, r0 = threadIdx.x >> 5;
  const float* xp = x + ((size_t)b * TLEN + t0) * CCH + c0;
  #pragma unroll
  for (int r = 0; r < 32; r += 8) tile[r + r0][col] = xp[(size_t)(r + r0) * CCH + col];
  __syncthreads();
  float* tp = xT + ((size_t)b * CCH + c0) * TLEN + t0;
  #pragma unroll
  for (int r = 0; r < 32; r += 8) tp[(size_t)(r + r0) * TLEN + col] = tile[col][r + r0];
}

// xvT[B,C,T] + x[B,T,C] -> xvar[B,T,C], xinv = x - xvar
__global__ __launch_bounds__(256) void finalize_t(const float* __restrict__ xvT, const float* __restrict__ x,
                                                  float* __restrict__ xvar, float* __restrict__ xinv) {
  __shared__ float tile[32][33];
  int t0 = blockIdx.x << 5, c0 = blockIdx.y << 5, b = blockIdx.z;
  int col = threadIdx.x & 31, r0 = threadIdx.x >> 5;
  const float* sp = xvT + ((size_t)b * CCH + c0) * TLEN + t0;
  #pragma unroll
  for (int r = 0; r < 32; r += 8) tile[r + r0][col] = sp[(size_t)(r + r0) * TLEN + col];
  __syncthreads();
  size_t base = ((size_t)b * TLEN + t0) * CCH + c0;
  #pragma unroll
  for (int r = 0; r < 32; r += 8) {
    size_t off = base + (size_t)(r + r0) * CCH + col;
    float v = tile[col][r + r0];
    float xv = x[off];
    xvar[off] = v;
    xinv[off] = xv - v;
  }
}

// xvT[B,C,T] -> xvar[B,T,C]  (fallback path, no workspace)
__global__ __launch_bounds__(256) void transpose_back(const float* __restrict__ xvT, float* __restrict__ xvar) {
  __shared__ float tile[32][33];
  int t0 = blockIdx.x << 5, c0 = blockIdx.y << 5, b = blockIdx.z;
  int col = threadIdx.x & 31, r0 = threadIdx.x >> 5;
  const float* sp = xvT + ((size_t)b * CCH + c0) * TLEN + t0;
  #pragma unroll
  for (int r = 0; r < 32; r += 8) tile[r + r0][col] = sp[(size_t)(r + r0) * TLEN + col];
  __syncthreads();
  size_t base = ((size_t)b * TLEN + t0) * CCH + c0;
  #pragma unroll
  for (int r = 0; r < 32; r += 8) xvar[base + (size_t)(r + r0) * CCH + col] = tile[col][r + r0];
}

__global__ __launch_bounds__(256) void sub_kernel(const float4* __restrict__ x, const float4* __restrict__ xv,
                                                  float4* __restrict__ xi, int n4) {
  int i = blockIdx.x * 256 + threadIdx.x;
  if (i < n4) {
    float4 a = x[i], b = xv[i];
    xi[i] = make_float4(a.x - b.x, a.y - b.y, a.z - b.z, a.w - b.w);
  }
}

extern "C" void kernel_launch(void* const* d_in, const int* in_sizes, int n_in,
                              void* d_out, int out_size, void* d_ws, size_t ws_size,
                              hipStream_t stream) {
  const float* x = (const float*)d_in[0];
  float* out  = (float*)d_out;
  float* xvar = out;
  float* xinv = out + HALF;

  bool use_ws = ws_size >= (size_t)NSER * TLEN * sizeof(float);
  float* buf = use_ws ? (float*)d_ws : xinv;   // fallback: stage in the x_inv output region

  dim3 tgrid(TLEN / 32, CCH / 32, BB);
  transpose_fwd<<<tgrid, 256, 0, stream>>>(x, buf);
  fourier_filter_series<<<NSER, 256, 0, stream>>>(buf);
  if (use_ws) {
    finalize_t<<<tgrid, 256, 0, stream>>>(buf, x, xvar, xinv);
  } else {
    transpose_back<<<tgrid, 256, 0, stream>>>(buf, xvar);
    sub_kernel<<<(HALF / 4 + 255) / 256, 256, 0, stream>>>((const float4*)x, (const float4*)xvar,
                                                           (float4*)xinv, HALF / 4);
  }
}

// Round 2
// 303.275 us; speedup vs baseline: 1.1419x; 1.1419x over previous
//
#include <hip/hip_runtime.h>

// FourierFilter: per-(b,c) rfft-4096 -> top-k (80% energy) spectral mask -> irfft.
// x:[32,4096,128] f32. out = concat(x_var, x_inv), each [32,4096,128].
// Pipeline: transpose -> per-series FFT/filter/iFFT (in-place, 17KB LDS) -> transpose back + subtract.

#define TLEN 4096
#define N2   2048
#define CCH  128
#define BB   32
#define NSER (BB * CCH)
#define HALF 16777216  // 32*4096*128
#define PI_F 3.14159265358979323846f

// LDS pad swizzle: +1 float per 32 to break power-of-2 bank strides
#define LP(i) ((i) + ((i) >> 5))

__device__ __forceinline__ void cmul(float& r, float& i, float br, float bi) {
  float tr = r * br - i * bi;
  i = r * bi + i * br;
  r = tr;
}

__device__ __forceinline__ void dft4(float vr[4], float vi[4], float s) {
  float t0r = vr[0] + vr[2], t0i = vi[0] + vi[2];
  float t1r = vr[0] - vr[2], t1i = vi[0] - vi[2];
  float t2r = vr[1] + vr[3], t2i = vi[1] + vi[3];
  float d3r = vr[1] - vr[3], d3i = vi[1] - vi[3];
  float t3r = -s * d3i, t3i = s * d3r;      // s*i*(v1-v3)
  vr[0] = t0r + t2r; vi[0] = t0i + t2i;
  vr[1] = t1r + t3r; vi[1] = t1i + t3i;
  vr[2] = t0r - t2r; vi[2] = t0i - t2i;
  vr[3] = t1r - t3r; vi[3] = t1i - t3i;
}

__device__ __forceinline__ void dft8(float vr[8], float vi[8], float s) {
  float er[4]  = {vr[0], vr[2], vr[4], vr[6]};
  float ei[4]  = {vi[0], vi[2], vi[4], vi[6]};
  float odr[4] = {vr[1], vr[3], vr[5], vr[7]};
  float odi[4] = {vi[1], vi[3], vi[5], vi[7]};
  dft4(er, ei, s);
  dft4(odr, odi, s);
  const float c = 0.70710678118654752440f;
  float wr[4] = {1.0f, c, 0.0f, -c};
  float wi[4] = {0.0f, s * c, s, s * c};    // w^k = e^{s*i*pi*k/4}
  #pragma unroll
  for (int k = 0; k < 4; ++k) {
    float tr = wr[k] * odr[k] - wi[k] * odi[k];
    float ti = wr[k] * odi[k] + wi[k] * odr[k];
    vr[k]     = er[k] + tr; vi[k]     = ei[k] + ti;
    vr[k + 4] = er[k] - tr; vi[k + 4] = ei[k] - ti;
  }
}

// Stockham radix-8 stage, Ns=1: all twiddles are 1 (p=0). 256 threads, j=tid.
__device__ __forceinline__ void stage8_first(float* zr, float* zi, int tid, float s) {
  float vr[8], vi[8];
  #pragma unroll
  for (int r = 0; r < 8; ++r) {
    int idx = LP(tid + (r << 8));
    vr[r] = zr[idx]; vi[r] = zi[idx];
  }
  dft8(vr, vi, s);
  __syncthreads();
  #pragma unroll
  for (int r = 0; r < 8; ++r) {
    int idx = LP((tid << 3) + r);
    zr[idx] = vr[r]; zi[idx] = vi[r];
  }
  __syncthreads();
}

// Stockham radix-8 stage with twiddles: 1 sincos + binary-powered complex mults.
template <int NS>
__device__ __forceinline__ void stage8_tw(float* zr, float* zi, int tid, float s) {
  int j = tid;
  int p = j & (NS - 1);
  float vr[8], vi[8];
  #pragma unroll
  for (int r = 0; r < 8; ++r) {
    int idx = LP(j + (r << 8));
    vr[r] = zr[idx]; vi[r] = zi[idx];
  }
  float ang = s * 6.28318530717958647692f * (float)p / (float)(NS * 8);
  float s1, c1; __sincosf(ang, &s1, &c1);
  float c2 = c1 * c1 - s1 * s1, s2 = 2.0f * c1 * s1;         // w^2
  float c3 = c2 * c1 - s2 * s1, s3 = c2 * s1 + s2 * c1;      // w^3
  float c4 = c2 * c2 - s2 * s2, s4 = 2.0f * c2 * s2;         // w^4
  float c5 = c4 * c1 - s4 * s1, s5 = c4 * s1 + s4 * c1;      // w^5
  float c6 = c4 * c2 - s4 * s2, s6 = c4 * s2 + s4 * c2;      // w^6
  float c7 = c4 * c3 - s4 * s3, s7 = c4 * s3 + s4 * c3;      // w^7
  cmul(vr[1], vi[1], c1, s1);
  cmul(vr[2], vi[2], c2, s2);
  cmul(vr[3], vi[3], c3, s3);
  cmul(vr[4], vi[4], c4, s4);
  cmul(vr[5], vi[5], c5, s5);
  cmul(vr[6], vi[6], c6, s6);
  cmul(vr[7], vi[7], c7, s7);
  dft8(vr, vi, s);
  __syncthreads();
  int idxD = ((j - p) << 3) + p;
  #pragma unroll
  for (int r = 0; r < 8; ++r) {
    int idx = LP(idxD + r * NS);
    zr[idx] = vr[r]; zi[idx] = vi[r];
  }
  __syncthreads();
}

// Final radix-4 stage, Ns=512: read/write slots coincide per j -> no intra-stage barrier.
__device__ __forceinline__ void stage4_last(float* zr, float* zi, int tid, float s) {
  #pragma unroll
  for (int half = 0; half < 2; ++half) {
    int j = tid + (half << 8);    // 0..511
    float ang = s * PI_F * (float)j * (1.0f / 1024.0f);   // 2*pi*j/2048
    float s1, c1; __sincosf(ang, &s1, &c1);
    float c2 = c1 * c1 - s1 * s1, s2 = 2.0f * c1 * s1;
    float c3 = c2 * c1 - s2 * s1, s3 = c2 * s1 + s2 * c1;
    float vr[4], vi[4];
    #pragma unroll
    for (int r = 0; r < 4; ++r) {
      int idx = LP(j + (r << 9));
      vr[r] = zr[idx]; vi[r] = zi[idx];
    }
    cmul(vr[1], vi[1], c1, s1);
    cmul(vr[2], vi[2], c2, s2);
    cmul(vr[3], vi[3], c3, s3);
    dft4(vr, vi, s);
    #pragma unroll
    for (int r = 0; r < 4; ++r) {
      int idx = LP(j + (r << 9));
      zr[idx] = vr[r]; zi[idx] = vi[r];
    }
  }
  __syncthreads();
}

__device__ __forceinline__ void fft2048(float* zr, float* zi, int tid, float s) {
  stage8_first(zr, zi, tid, s);
  stage8_tw<8>(zr, zi, tid, s);
  stage8_tw<64>(zr, zi, tid, s);
  stage4_last(zr, zi, tid, s);
}

// Float block reduction, ONE barrier; caller alternates `bank` (double-buffered scratch).
__device__ __forceinline__ float block_sum(float v, float* red, int tid, int bank) {
  #pragma unroll
  for (int o = 32; o > 0; o >>= 1) v += __shfl_down(v, o, 64);
  if ((tid & 63) == 0) red[(bank << 2) + (tid >> 6)] = v;
  __syncthreads();
  int b4 = bank << 2;
  return red[b4] + red[b4 + 1] + red[b4 + 2] + red[b4 + 3];
}

// One block (256 thr) per series. buf layout: [series][4096] contiguous. In-place filter.
// LDS: z arrays only (~17KB); rfft spectrum X overlays z in place (pairing (k,2048-k) is
// per-thread private, so unpack and repack need no barriers).
__global__ __launch_bounds__(256) void fourier_filter_series(float* __restrict__ buf) {
  __shared__ float zr[2113], zi[2113];   // LP(2048)=2112
  __shared__ float red[8];
  int tid = threadIdx.x;
  float* p = buf + (size_t)blockIdx.x * TLEN;

  // Load packed: z[m] = x[2m] + i*x[2m+1]
  const float2* p2 = (const float2*)p;
  #pragma unroll
  for (int k = tid; k < N2; k += 256) {
    float2 v = p2[k];
    zr[LP(k)] = v.x; zi[LP(k)] = v.y;
  }
  __syncthreads();

  fft2048(zr, zi, tid, -1.0f);   // forward

  // Unpack to rfft bins X[0..2048], IN PLACE. Thread owns pairs (k, 2048-k), k=tid+256*jj.
  // E=(Z[k]+conj(Z[N-k]))/2, O=-i/2(Z[k]-conj(Z[N-k])), X[k]=E+W*O, W=e^{-i pi k/2048},
  // X[2048-k]=conj(E-W*O). Energies stay in registers for the selection.
  float eb[9];
  eb[8] = 0.0f;
  const float RC  = 0.92387953251128675613f;   // cos(pi/8)
  const float RSn = -0.38268343236508977173f;  // -sin(pi/8)
  float ws, wc;
  __sincosf(-PI_F * (float)tid * (1.0f / 2048.0f), &ws, &wc);
  #pragma unroll
  for (int jj = 0; jj < 4; ++jj) {
    int k = tid + (jj << 8);
    int mkz = (N2 - k) & (N2 - 1);
    int ik = LP(k), im = LP(N2 - k);
    float akr = zr[ik],      aki = zi[ik];
    float bkr = zr[LP(mkz)], bki = zi[LP(mkz)];
    float Er  = 0.5f * (akr + bkr);
    float Ei  = 0.5f * (aki - bki);
    float Or_ = 0.5f * (aki + bki);
    float Oi  = 0.5f * (bkr - akr);
    float tr = wc * Or_ - ws * Oi;
    float ti = wc * Oi + ws * Or_;
    float x0r = Er + tr, x0i = Ei + ti;
    float x1r = Er - tr, x1i = ti - Ei;
    zr[ik] = x0r; zi[ik] = x0i;
    zr[im] = x1r; zi[im] = x1i;
    eb[2 * jj]     = x0r * x0r + x0i * x0i;
    eb[2 * jj + 1] = x1r * x1r + x1i * x1i;
    float nwc = wc * RC - ws * RSn;
    ws = wc * RSn + ws * RC; wc = nwc;
  }
  if (tid == 0) {               // k=1024 self-pair: X[1024] = (Re, -Im)
    int i4 = LP(1024);
    float re = zr[i4], im_ = zi[i4];
    zi[i4] = -im_;
    eb[8] = re * re + im_ * im_;
  }

  // Selection: tau = E_k = max tau s.t. sum(e >= tau) > 0.8*total (float sums).
  float tloc = 0.0f;
  #pragma unroll
  for (int s = 0; s < 9; ++s) tloc += eb[s];
  float total = block_sum(tloc, red, tid, 0);
  float thresh = 0.8f * total;

  unsigned lo = 0u, hi = 0x7F7FFFFFu;
  for (int it = 0; it < 31; ++it) {
    unsigned mid = (lo + hi + 1u) >> 1;
    float tau = __uint_as_float(mid);
    float loc = 0.0f;
    #pragma unroll
    for (int s = 0; s < 9; ++s) loc += (eb[s] >= tau) ? eb[s] : 0.0f;
    float ssum = block_sum(loc, red, tid, (it + 1) & 1);
    if (ssum > thresh) lo = mid; else hi = mid - 1;
  }
  float tau = __uint_as_float(lo);

  // Mask + hermitian repack IN PLACE (same per-thread pairs; no barrier needed).
  // Z[k] = (Er-Oi) + i(Ei+Or); Z[2048-k] = (Er+Oi) + i(-Ei+Or), w = e^{+i pi k/2048}.
  const float RSp = 0.38268343236508977173f;   // +sin(pi/8)
  __sincosf(PI_F * (float)tid * (1.0f / 2048.0f), &ws, &wc);
  #pragma unroll
  for (int jj = 0; jj < 4; ++jj) {
    int k = tid + (jj << 8);
    int ik = LP(k), im = LP(N2 - k);
    float xkr = zr[ik], xki = zi[ik];
    float xmr = zr[im], xmi = zi[im];
    float ekk = xkr * xkr + xki * xki;
    float emm = xmr * xmr + xmi * xmi;
    if (ekk >= tau) { xkr = 0.0f; xki = 0.0f; }
    if (emm >= tau) { xmr = 0.0f; xmi = 0.0f; }
    float Er = 0.5f * (xkr + xmr);
    float Ei = 0.5f * (xki - xmi);
    float Br = 0.5f * (xkr - xmr);
    float Bi = 0.5f * (xki + xmi);
    float Or_ = wc * Br - ws * Bi;
    float Oi  = wc * Bi + ws * Br;
    zr[ik] = Er - Oi;  zi[ik] = Ei + Or_;
    zr[im] = Er + Oi;  zi[im] = Or_ - Ei;   // k=0 writes slot 2048: outside iFFT range, harmless
    float nwc = wc * RC - ws * RSp;
    ws = wc * RSp + ws * RC; wc = nwc;
  }
  if (tid == 0) {               // k=1024: Z[1024] = conj(masked X[1024])
    int i4 = LP(1024);
    float re = zr[i4], im_ = zi[i4];
    float e = re * re + im_ * im_;
    if (e >= tau) { re = 0.0f; im_ = 0.0f; }
    zr[i4] = re; zi[i4] = -im_;
  }
  __syncthreads();

  fft2048(zr, zi, tid, 1.0f);    // inverse (unscaled)

  const float scale = 1.0f / 2048.0f;
  float2* po = (float2*)p;
  #pragma unroll
  for (int k = tid; k < N2; k += 256) {
    float2 v;
    v.x = zr[LP(k)] * scale;
    v.y = zi[LP(k)] * scale;
    po[k] = v;
  }
}

// x[B,T,C] -> xT[B,C,T].  64x64 tiles, float4 both sides (256B segments).
__global__ __launch_bounds__(256) void transpose_fwd(const float* __restrict__ x, float* __restrict__ xT) {
  __shared__ float tile[64][65];
  int t0 = blockIdx.x << 6, c0 = blockIdx.y << 6, b = blockIdx.z;
  int m = threadIdx.x & 15, q = threadIdx.x >> 4;
  #pragma unroll
  for (int r = 0; r < 4; ++r) {
    int t = q + (r << 4);
    float4 v = *(const float4*)(x + ((size_t)b * TLEN + t0 + t) * CCH + c0 + (m << 2));
    tile[t][(m << 2) + 0] = v.x; tile[t][(m << 2) + 1] = v.y;
    tile[t][(m << 2) + 2] = v.z; tile[t][(m << 2) + 3] = v.w;
  }
  __syncthreads();
  #pragma unroll
  for (int r = 0; r < 4; ++r) {
    int c = q + (r << 4);
    int t4 = m << 2;
    float4 v;
    v.x = tile[t4 + 0][c]; v.y = tile[t4 + 1][c];
    v.z = tile[t4 + 2][c]; v.w = tile[t4 + 3][c];
    *(float4*)(xT + ((size_t)b * CCH + c0 + c) * TLEN + t0 + t4) = v;
  }
}

// xvT[B,C,T] + x[B,T,C] -> xvar[B,T,C], xinv = x - xvar.  64x64 tiles, float4.
__global__ __launch_bounds__(256) void finalize_t(const float* __restrict__ xvT, const float* __restrict__ x,
                                                  float* __restrict__ xvar, float* __restrict__ xinv) {
  __shared__ float tile[64][65];
  int t0 = blockIdx.x << 6, c0 = blockIdx.y << 6, b = blockIdx.z;
  int m = threadIdx.x & 15, q = threadIdx.x >> 4;
  #pragma unroll
  for (int r = 0; r < 4; ++r) {
    int c = q + (r << 4);
    int t4 = m << 2;
    float4 v = *(const float4*)(xvT + ((size_t)b * CCH + c0 + c) * TLEN + t0 + t4);
    tile[t4 + 0][c] = v.x; tile[t4 + 1][c] = v.y;
    tile[t4 + 2][c] = v.z; tile[t4 + 3][c] = v.w;
  }
  __syncthreads();
  #pragma unroll
  for (int r = 0; r < 4; ++r) {
    int t = q + (r << 4);
    int c4 = m << 2;
    float4 v;
    v.x = tile[t][c4 + 0]; v.y = tile[t][c4 + 1];
    v.z = tile[t][c4 + 2]; v.w = tile[t][c4 + 3];
    size_t off = ((size_t)b * TLEN + t0 + t) * CCH + c0 + c4;
    float4 xv = *(const float4*)(x + off);
    *(float4*)(xvar + off) = v;
    *(float4*)(xinv + off) = make_float4(xv.x - v.x, xv.y - v.y, xv.z - v.z, xv.w - v.w);
  }
}

// xvT[B,C,T] -> xvar[B,T,C]  (fallback path, no workspace)
__global__ __launch_bounds__(256) void transpose_back(const float* __restrict__ xvT, float* __restrict__ xvar) {
  __shared__ float tile[64][65];
  int t0 = blockIdx.x << 6, c0 = blockIdx.y << 6, b = blockIdx.z;
  int m = threadIdx.x & 15, q = threadIdx.x >> 4;
  #pragma unroll
  for (int r = 0; r < 4; ++r) {
    int c = q + (r << 4);
    int t4 = m << 2;
    float4 v = *(const float4*)(xvT + ((size_t)b * CCH + c0 + c) * TLEN + t0 + t4);
    tile[t4 + 0][c] = v.x; tile[t4 + 1][c] = v.y;
    tile[t4 + 2][c] = v.z; tile[t4 + 3][c] = v.w;
  }
  __syncthreads();
  #pragma unroll
  for (int r = 0; r < 4; ++r) {
    int t = q + (r << 4);
    int c4 = m << 2;
    float4 v;
    v.x = tile[t][c4 + 0]; v.y = tile[t][c4 + 1];
    v.z = tile[t][c4 + 2]; v.w = tile[t][c4 + 3];
    size_t off = ((size_t)b * TLEN + t0 + t) * CCH + c0 + c4;
    *(float4*)(xvar + off) = v;
  }
}

__global__ __launch_bounds__(256) void sub_kernel(const float4* __restrict__ x, const float4* __restrict__ xv,
                                                  float4* __restrict__ xi, int n4) {
  int i = blockIdx.x * 256 + threadIdx.x;
  if (i < n4) {
    float4 a = x[i], b = xv[i];
    xi[i] = make_float4(a.x - b.x, a.y - b.y, a.z - b.z, a.w - b.w);
  }
}

extern "C" void kernel_launch(void* const* d_in, const int* in_sizes, int n_in,
                              void* d_out, int out_size, void* d_ws, size_t ws_size,
                              hipStream_t stream) {
  const float* x = (const float*)d_in[0];
  float* out  = (float*)d_out;
  float* xvar = out;
  float* xinv = out + HALF;

  bool use_ws = ws_size >= (size_t)NSER * TLEN * sizeof(float);
  float* buf = use_ws ? (float*)d_ws : xinv;   // fallback: stage in the x_inv output region

  dim3 tgrid(TLEN / 64, CCH / 64, BB);
  transpose_fwd<<<tgrid, 256, 0, stream>>>(x, buf);
  fourier_filter_series<<<NSER, 256, 0, stream>>>(buf);
  if (use_ws) {
    finalize_t<<<tgrid, 256, 0, stream>>>(buf, x, xvar, xinv);
  } else {
    transpose_back<<<tgrid, 256, 0, stream>>>(buf, xvar);
    sub_kernel<<<(HALF / 4 + 255) / 256, 256, 0, stream>>>((const float4*)x, (const float4*)xvar,
                                                           (float4*)xinv, HALF / 4);
  }
}

// Round 3
// 300.704 us; speedup vs baseline: 1.1517x; 1.0086x over previous
//
#include <hip/hip_runtime.h>

// FourierFilter: per-(b,c) rfft-4096 -> top-k (80% energy) spectral mask -> irfft.
// x:[32,4096,128] f32. out = concat(x_var, x_inv), each [32,4096,128].
// Pipeline: tile-transpose -> per-series FFT/filter/iFFT (in-place, 17KB LDS) -> finalize.
// Intermediate buf layout is TILED: buf[B][NT=64][C=128][TS=64], so every global access in
// the transpose kernels is a contiguous >=512B stream (DRAM-friendly); the filter reads its
// series as 64 x 256B segments (L3-resident, latency-tolerant).

#define TLEN 4096
#define N2   2048
#define CCH  128
#define BB   32
#define NSER (BB * CCH)
#define HALF 16777216  // 32*4096*128
#define PI_F 3.14159265358979323846f
#define NT   64
#define TS   64
#define SLAB (CCH * TS)   // 8192 floats = 32KB per (b,tb) slab

// LDS pad swizzle for FFT arrays
#define LP(i) ((i) + ((i) >> 5))

__device__ __forceinline__ void cmul(float& r, float& i, float br, float bi) {
  float tr = r * br - i * bi;
  i = r * bi + i * br;
  r = tr;
}

__device__ __forceinline__ void dft4(float vr[4], float vi[4], float s) {
  float t0r = vr[0] + vr[2], t0i = vi[0] + vi[2];
  float t1r = vr[0] - vr[2], t1i = vi[0] - vi[2];
  float t2r = vr[1] + vr[3], t2i = vi[1] + vi[3];
  float d3r = vr[1] - vr[3], d3i = vi[1] - vi[3];
  float t3r = -s * d3i, t3i = s * d3r;
  vr[0] = t0r + t2r; vi[0] = t0i + t2i;
  vr[1] = t1r + t3r; vi[1] = t1i + t3i;
  vr[2] = t0r - t2r; vi[2] = t0i - t2i;
  vr[3] = t1r - t3r; vi[3] = t1i - t3i;
}

__device__ __forceinline__ void dft8(float vr[8], float vi[8], float s) {
  float er[4]  = {vr[0], vr[2], vr[4], vr[6]};
  float ei[4]  = {vi[0], vi[2], vi[4], vi[6]};
  float odr[4] = {vr[1], vr[3], vr[5], vr[7]};
  float odi[4] = {vi[1], vi[3], vi[5], vi[7]};
  dft4(er, ei, s);
  dft4(odr, odi, s);
  const float c = 0.70710678118654752440f;
  float wr[4] = {1.0f, c, 0.0f, -c};
  float wi[4] = {0.0f, s * c, s, s * c};
  #pragma unroll
  for (int k = 0; k < 4; ++k) {
    float tr = wr[k] * odr[k] - wi[k] * odi[k];
    float ti = wr[k] * odi[k] + wi[k] * odr[k];
    vr[k]     = er[k] + tr; vi[k]     = ei[k] + ti;
    vr[k + 4] = er[k] - tr; vi[k + 4] = ei[k] - ti;
  }
}

__device__ __forceinline__ void stage8_first(float* zr, float* zi, int tid, float s) {
  float vr[8], vi[8];
  #pragma unroll
  for (int r = 0; r < 8; ++r) {
    int idx = LP(tid + (r << 8));
    vr[r] = zr[idx]; vi[r] = zi[idx];
  }
  dft8(vr, vi, s);
  __syncthreads();
  #pragma unroll
  for (int r = 0; r < 8; ++r) {
    int idx = LP((tid << 3) + r);
    zr[idx] = vr[r]; zi[idx] = vi[r];
  }
  __syncthreads();
}

template <int NS>
__device__ __forceinline__ void stage8_tw(float* zr, float* zi, int tid, float s) {
  int j = tid;
  int p = j & (NS - 1);
  float vr[8], vi[8];
  #pragma unroll
  for (int r = 0; r < 8; ++r) {
    int idx = LP(j + (r << 8));
    vr[r] = zr[idx]; vi[r] = zi[idx];
  }
  float ang = s * 6.28318530717958647692f * (float)p / (float)(NS * 8);
  float s1, c1; __sincosf(ang, &s1, &c1);
  float c2 = c1 * c1 - s1 * s1, s2 = 2.0f * c1 * s1;
  float c3 = c2 * c1 - s2 * s1, s3 = c2 * s1 + s2 * c1;
  float c4 = c2 * c2 - s2 * s2, s4 = 2.0f * c2 * s2;
  float c5 = c4 * c1 - s4 * s1, s5 = c4 * s1 + s4 * c1;
  float c6 = c4 * c2 - s4 * s2, s6 = c4 * s2 + s4 * c2;
  float c7 = c4 * c3 - s4 * s3, s7 = c4 * s3 + s4 * c3;
  cmul(vr[1], vi[1], c1, s1);
  cmul(vr[2], vi[2], c2, s2);
  cmul(vr[3], vi[3], c3, s3);
  cmul(vr[4], vi[4], c4, s4);
  cmul(vr[5], vi[5], c5, s5);
  cmul(vr[6], vi[6], c6, s6);
  cmul(vr[7], vi[7], c7, s7);
  dft8(vr, vi, s);
  __syncthreads();
  int idxD = ((j - p) << 3) + p;
  #pragma unroll
  for (int r = 0; r < 8; ++r) {
    int idx = LP(idxD + r * NS);
    zr[idx] = vr[r]; zi[idx] = vi[r];
  }
  __syncthreads();
}

__device__ __forceinline__ void stage4_last(float* zr, float* zi, int tid, float s) {
  #pragma unroll
  for (int half = 0; half < 2; ++half) {
    int j = tid + (half << 8);
    float ang = s * PI_F * (float)j * (1.0f / 1024.0f);
    float s1, c1; __sincosf(ang, &s1, &c1);
    float c2 = c1 * c1 - s1 * s1, s2 = 2.0f * c1 * s1;
    float c3 = c2 * c1 - s2 * s1, s3 = c2 * s1 + s2 * c1;
    float vr[4], vi[4];
    #pragma unroll
    for (int r = 0; r < 4; ++r) {
      int idx = LP(j + (r << 9));
      vr[r] = zr[idx]; vi[r] = zi[idx];
    }
    cmul(vr[1], vi[1], c1, s1);
    cmul(vr[2], vi[2], c2, s2);
    cmul(vr[3], vi[3], c3, s3);
    dft4(vr, vi, s);
    #pragma unroll
    for (int r = 0; r < 4; ++r) {
      int idx = LP(j + (r << 9));
      zr[idx] = vr[r]; zi[idx] = vi[r];
    }
  }
  __syncthreads();
}

__device__ __forceinline__ void fft2048(float* zr, float* zi, int tid, float s) {
  stage8_first(zr, zi, tid, s);
  stage8_tw<8>(zr, zi, tid, s);
  stage8_tw<64>(zr, zi, tid, s);
  stage4_last(zr, zi, tid, s);
}

__device__ __forceinline__ float block_sum(float v, float* red, int tid, int bank) {
  #pragma unroll
  for (int o = 32; o > 0; o >>= 1) v += __shfl_down(v, o, 64);
  if ((tid & 63) == 0) red[(bank << 2) + (tid >> 6)] = v;
  __syncthreads();
  int b4 = bank << 2;
  return red[b4] + red[b4 + 1] + red[b4 + 2] + red[b4 + 3];
}

// One block (256 thr) per series. Series elements live in buf tiled layout.
__global__ __launch_bounds__(256) void fourier_filter_series(float* __restrict__ buf) {
  __shared__ float zr[2113], zi[2113];
  __shared__ float red[8];
  int tid = threadIdx.x;
  int b = blockIdx.x >> 7, c = blockIdx.x & 127;
  float* bufp = buf + (size_t)b * (NT * SLAB) + (size_t)c * TS;

  // Load packed: z[k] = x[2k] + i*x[2k+1]; element t at bufp[(t>>6)*SLAB + (t&63)]
  #pragma unroll
  for (int j = 0; j < 8; ++j) {
    int k = tid + (j << 8);
    int off = ((k >> 5) << 13) + ((k & 31) << 1);
    float2 v = *(const float2*)(bufp + off);
    zr[LP(k)] = v.x; zi[LP(k)] = v.y;
  }
  __syncthreads();

  fft2048(zr, zi, tid, -1.0f);   // forward

  // Unpack to rfft bins X[0..2048] IN PLACE (per-thread pairs (k,2048-k)); energies in regs.
  float eb[9];
  eb[8] = 0.0f;
  const float RC  = 0.92387953251128675613f;   // cos(pi/8)
  const float RSn = -0.38268343236508977173f;  // -sin(pi/8)
  float ws, wc;
  __sincosf(-PI_F * (float)tid * (1.0f / 2048.0f), &ws, &wc);
  #pragma unroll
  for (int jj = 0; jj < 4; ++jj) {
    int k = tid + (jj << 8);
    int mkz = (N2 - k) & (N2 - 1);
    int ik = LP(k), im = LP(N2 - k);
    float akr = zr[ik],      aki = zi[ik];
    float bkr = zr[LP(mkz)], bki = zi[LP(mkz)];
    float Er  = 0.5f * (akr + bkr);
    float Ei  = 0.5f * (aki - bki);
    float Or_ = 0.5f * (aki + bki);
    float Oi  = 0.5f * (bkr - akr);
    float tr = wc * Or_ - ws * Oi;
    float ti = wc * Oi + ws * Or_;
    float x0r = Er + tr, x0i = Ei + ti;
    float x1r = Er - tr, x1i = ti - Ei;
    zr[ik] = x0r; zi[ik] = x0i;
    zr[im] = x1r; zi[im] = x1i;
    eb[2 * jj]     = x0r * x0r + x0i * x0i;
    eb[2 * jj + 1] = x1r * x1r + x1i * x1i;
    float nwc = wc * RC - ws * RSn;
    ws = wc * RSn + ws * RC; wc = nwc;
  }
  if (tid == 0) {
    int i4 = LP(1024);
    float re = zr[i4], im_ = zi[i4];
    zi[i4] = -im_;
    eb[8] = re * re + im_ * im_;
  }

  // Selection: tau = max tau s.t. sum(e >= tau) > 0.8*total.
  float tloc = 0.0f;
  #pragma unroll
  for (int s = 0; s < 9; ++s) tloc += eb[s];
  float total = block_sum(tloc, red, tid, 0);
  float thresh = 0.8f * total;

  unsigned lo = 0u, hi = 0x7F7FFFFFu;
  for (int it = 0; it < 31; ++it) {
    unsigned mid = (lo + hi + 1u) >> 1;
    float tau = __uint_as_float(mid);
    float loc = 0.0f;
    #pragma unroll
    for (int s = 0; s < 9; ++s) loc += (eb[s] >= tau) ? eb[s] : 0.0f;
    float ssum = block_sum(loc, red, tid, (it + 1) & 1);
    if (ssum > thresh) lo = mid; else hi = mid - 1;
  }
  float tau = __uint_as_float(lo);

  // Mask + hermitian repack IN PLACE.
  const float RSp = 0.38268343236508977173f;
  __sincosf(PI_F * (float)tid * (1.0f / 2048.0f), &ws, &wc);
  #pragma unroll
  for (int jj = 0; jj < 4; ++jj) {
    int k = tid + (jj << 8);
    int ik = LP(k), im = LP(N2 - k);
    float xkr = zr[ik], xki = zi[ik];
    float xmr = zr[im], xmi = zi[im];
    float ekk = xkr * xkr + xki * xki;
    float emm = xmr * xmr + xmi * xmi;
    if (ekk >= tau) { xkr = 0.0f; xki = 0.0f; }
    if (emm >= tau) { xmr = 0.0f; xmi = 0.0f; }
    float Er = 0.5f * (xkr + xmr);
    float Ei = 0.5f * (xki - xmi);
    float Br = 0.5f * (xkr - xmr);
    float Bi = 0.5f * (xki + xmi);
    float Or_ = wc * Br - ws * Bi;
    float Oi  = wc * Bi + ws * Br;
    zr[ik] = Er - Oi;  zi[ik] = Ei + Or_;
    zr[im] = Er + Oi;  zi[im] = Or_ - Ei;
    float nwc = wc * RC - ws * RSp;
    ws = wc * RSp + ws * RC; wc = nwc;
  }
  if (tid == 0) {
    int i4 = LP(1024);
    float re = zr[i4], im_ = zi[i4];
    float e = re * re + im_ * im_;
    if (e >= tau) { re = 0.0f; im_ = 0.0f; }
    zr[i4] = re; zi[i4] = -im_;
  }
  __syncthreads();

  fft2048(zr, zi, tid, 1.0f);    // inverse (unscaled)

  const float scale = 1.0f / 2048.0f;
  #pragma unroll
  for (int j = 0; j < 8; ++j) {
    int k = tid + (j << 8);
    int off = ((k >> 5) << 13) + ((k & 31) << 1);
    float2 v;
    v.x = zr[LP(k)] * scale;
    v.y = zi[LP(k)] * scale;
    *(float2*)(bufp + off) = v;
  }
}

// x[B,T,C] -> buf[B][NT][C][TS].  Block (tb,b): read 64 full 512B rows, write 32KB contiguous.
__global__ __launch_bounds__(512) void transpose_fwd(const float* __restrict__ x, float* __restrict__ buf) {
  __shared__ float lds[CCH * 65];   // lds[c*65 + r]
  int tb = blockIdx.x, b = blockIdx.y;
  const float* xp = x + ((size_t)b * TLEN + (size_t)tb * TS) * CCH;
  #pragma unroll
  for (int it = 0; it < 4; ++it) {
    int idx = threadIdx.x + (it << 9);
    int r = idx >> 5, c4 = (idx & 31) << 2;
    float4 v = *(const float4*)(xp + (size_t)r * CCH + c4);
    lds[(c4 + 0) * 65 + r] = v.x;
    lds[(c4 + 1) * 65 + r] = v.y;
    lds[(c4 + 2) * 65 + r] = v.z;
    lds[(c4 + 3) * 65 + r] = v.w;
  }
  __syncthreads();
  float* op = buf + ((size_t)b * NT + tb) * SLAB;
  #pragma unroll
  for (int it = 0; it < 4; ++it) {
    int idx = threadIdx.x + (it << 9);
    int c = idx >> 4, s4 = (idx & 15) << 2;
    float4 v;
    v.x = lds[c * 65 + s4 + 0];
    v.y = lds[c * 65 + s4 + 1];
    v.z = lds[c * 65 + s4 + 2];
    v.w = lds[c * 65 + s4 + 3];
    *(float4*)(op + c * TS + s4) = v;
  }
}

// buf[B][NT][C][TS] + x[B,T,C] -> xvar[B,T,C], xinv = x - xvar.
// Block (tb,b): read 32KB contiguous slab, write full coalesced rows.
// NOTE: safe when buf aliases xinv (block's slab == block's xinv range; reads precede writes).
__global__ __launch_bounds__(512) void finalize_t(const float* __restrict__ buf, const float* __restrict__ x,
                                                  float* __restrict__ xvar, float* __restrict__ xinv) {
  __shared__ float lds[TS * 132];   // lds[t*132 + c]
  int tb = blockIdx.x, b = blockIdx.y;
  const float* ip = buf + ((size_t)b * NT + tb) * SLAB;
  #pragma unroll
  for (int it = 0; it < 4; ++it) {
    int idx = threadIdx.x + (it << 9);
    int c = idx >> 4, s4 = (idx & 15) << 2;
    float4 v = *(const float4*)(ip + c * TS + s4);
    lds[(s4 + 0) * 132 + c] = v.x;
    lds[(s4 + 1) * 132 + c] = v.y;
    lds[(s4 + 2) * 132 + c] = v.z;
    lds[(s4 + 3) * 132 + c] = v.w;
  }
  __syncthreads();
  size_t rowbase = ((size_t)b * TLEN + (size_t)tb * TS) * CCH;
  #pragma unroll
  for (int it = 0; it < 4; ++it) {
    int idx = threadIdx.x + (it << 9);
    int t = idx >> 5, c4 = (idx & 31) << 2;
    float4 v = *(const float4*)(&lds[t * 132 + c4]);
    size_t off = rowbase + (size_t)t * CCH + c4;
    float4 xv = *(const float4*)(x + off);
    *(float4*)(xvar + off) = v;
    *(float4*)(xinv + off) = make_float4(xv.x - v.x, xv.y - v.y, xv.z - v.z, xv.w - v.w);
  }
}

extern "C" void kernel_launch(void* const* d_in, const int* in_sizes, int n_in,
                              void* d_out, int out_size, void* d_ws, size_t ws_size,
                              hipStream_t stream) {
  const float* x = (const float*)d_in[0];
  float* out  = (float*)d_out;
  float* xvar = out;
  float* xinv = out + HALF;

  bool use_ws = ws_size >= (size_t)HALF * sizeof(float);
  float* buf = use_ws ? (float*)d_ws : xinv;   // fallback: stage tiled buf in x_inv region (aliasing-safe)

  dim3 tgrid(NT, BB);
  transpose_fwd<<<tgrid, 512, 0, stream>>>(x, buf);
  fourier_filter_series<<<NSER, 256, 0, stream>>>(buf);
  finalize_t<<<tgrid, 512, 0, stream>>>(buf, x, xvar, xinv);
}